// Round 5
// baseline (149.301 us; speedup 1.0000x reference)
//
#include <hip/hip_runtime.h>

#define F 32  // F_IN == F_OUT == 32

typedef __attribute__((ext_vector_type(8))) unsigned short us8;
typedef __attribute__((ext_vector_type(4))) float f4;

// ---- bf16 helpers (manual RNE) ----
static __device__ __forceinline__ unsigned short f2bf(float f) {
    unsigned int u = __float_as_uint(f);
    u += 0x7FFF + ((u >> 16) & 1);
    return (unsigned short)(u >> 16);
}
static __device__ __forceinline__ float bf2f(unsigned short s) {
    return __uint_as_float(((unsigned int)s) << 16);
}

// Fused prologue. Blocks [0, nxw): y = x @ W^T in bf16 (8 nodes/block).
// Blocks [nxw, ...): CSR row-ptr boundary scatter from sorted rows.
// Branch is blockIdx-uniform -> no divergence; __syncthreads only on xw path.
__global__ __launch_bounds__(256) void prologue_kernel(
    const float* __restrict__ x, const float* __restrict__ W,
    const int* __restrict__ rows,
    unsigned short* __restrict__ y, int* __restrict__ ptr,
    int N, int E, int nxw) {
    int b = blockIdx.x;
    int t = threadIdx.x;
    if (b < nxw) {
        __shared__ float Wt[F * F];   // Wt[fi*32+fo]
        __shared__ float xs[8 * F];
        #pragma unroll
        for (int k = 0; k < 4; ++k) {
            int i = t + k * 256;
            Wt[(i & 31) * F + (i >> 5)] = W[i];
        }
        int n0 = b * 8;
        int gi = n0 * F + t;
        xs[t] = (gi < N * F) ? x[gi] : 0.0f;
        __syncthreads();
        int nl = t >> 5, fo = t & 31;
        float acc = 0.0f;
        #pragma unroll
        for (int fi = 0; fi < F; ++fi)
            acc = fmaf(xs[nl * F + fi], Wt[fi * F + fo], acc);
        int n = n0 + nl;
        if (n < N) y[n * F + fo] = f2bf(acc);
    } else {
        int e = (b - nxw) * 256 + t;
        if (e > E) return;
        int prev = (e == 0) ? -1 : rows[e - 1];
        int cur  = (e == E) ? N  : rows[e];
        for (int r = prev + 1; r <= cur; ++r) ptr[r] = e;
    }
}

// Hot kernel: wave = 16 nodes x 4 lanes. Lane l of group g loads ushort8
// (16B = features 8l..8l+7 of a bf16 row; 4 lanes cover the 64B row).
// Unroll x4 with clamped-index predication (no branches) -> up to 64 row
// gathers in flight per wave. Phase-ordered loads (cols -> vals -> rows ->
// FMA) so VMEM issues back-to-back. Zero LDS, zero shuffles.
__global__ __launch_bounds__(256) void gnn_kernel(
    const unsigned short* __restrict__ y,
    const int*   __restrict__ cols,
    const float* __restrict__ vals,
    const int*   __restrict__ row_ptr,
    const float* __restrict__ bias,
    float*       __restrict__ out, int N) {
    int t = threadIdx.x;
    int lane = t & 63;
    int g = lane >> 2;           // node group 0..15
    int l = lane & 3;            // feature slice: 8l..8l+7
    int n = (blockIdx.x * 4 + (t >> 6)) * 16 + g;
    int start = 0, end = 0;
    if (n < N) { start = row_ptr[n]; end = row_ptr[n + 1]; }

    const us8* __restrict__ y8 = (const us8*)y;   // 4 x ushort8 per row

    float a0[8], a1[8];
    #pragma unroll
    for (int i = 0; i < 8; ++i) { a0[i] = 0.f; a1[i] = 0.f; }

    for (int e = start; e < end; e += 4) {
        int ec[4];
        #pragma unroll
        for (int k = 0; k < 4; ++k) {
            int ek = e + k;
            ec[k] = (ek < end) ? ek : (end - 1);   // clamp: always in-range
        }
        int c[4];
        #pragma unroll
        for (int k = 0; k < 4; ++k)
            c[k] = __builtin_nontemporal_load(&cols[ec[k]]);
        float v[4];
        #pragma unroll
        for (int k = 0; k < 4; ++k) {
            float vv = __builtin_nontemporal_load(&vals[ec[k]]);
            v[k] = (e + k < end) ? vv : 0.0f;      // predicate via value
        }
        us8 r[4];
        #pragma unroll
        for (int k = 0; k < 4; ++k)
            r[k] = y8[c[k] * 4 + l];
        #pragma unroll
        for (int k = 0; k < 4; ++k) {
            float* a = (k & 1) ? a1 : a0;          // 2 chains -> shorter deps
            #pragma unroll
            for (int i = 0; i < 8; ++i)
                a[i] = fmaf(bf2f(r[k][i]), v[k], a[i]);
        }
    }

    if (n < N) {
        const float* __restrict__ bp = bias + l * 8;
        f4 o0, o1;
        o0.x = fmaxf(a0[0] + a1[0] + bp[0], 0.f);
        o0.y = fmaxf(a0[1] + a1[1] + bp[1], 0.f);
        o0.z = fmaxf(a0[2] + a1[2] + bp[2], 0.f);
        o0.w = fmaxf(a0[3] + a1[3] + bp[3], 0.f);
        o1.x = fmaxf(a0[4] + a1[4] + bp[4], 0.f);
        o1.y = fmaxf(a0[5] + a1[5] + bp[5], 0.f);
        o1.z = fmaxf(a0[6] + a1[6] + bp[6], 0.f);
        o1.w = fmaxf(a0[7] + a1[7] + bp[7], 0.f);
        f4* op = (f4*)(out + n * F + l * 8);
        __builtin_nontemporal_store(o0, op);
        __builtin_nontemporal_store(o1, op + 1);
    }
}

// ---- Fallback (ws too small): round-2 proven fp32 kernel ----
__global__ __launch_bounds__(256) void gnn_fp32_kernel(
    const float* __restrict__ x,
    const int*   __restrict__ rows,
    const int*   __restrict__ cols,
    const float* __restrict__ vals,
    const float* __restrict__ W,
    const float* __restrict__ bias,
    float*       __restrict__ out,
    int N, int E) {
    __shared__ float Wt[F * F];
    __shared__ float bS[F];
    int t = threadIdx.x;
    for (int i = t; i < F * F; i += 256)
        Wt[(i & 31) * F + (i >> 5)] = W[i];
    if (t < F) bS[t] = bias[t];
    __syncthreads();
    int lane = t & 63;
    int n = blockIdx.x * 4 + (t >> 6);
    if (n >= N) return;
    int g = lane >> 3, l = lane & 7;
    int target = n + (lane >> 5);
    int lo = 0, hi = E;
    while (lo < hi) { int mid = (lo + hi) >> 1; if (rows[mid] < target) lo = mid + 1; else hi = mid; }
    int start = __shfl(lo, 0), end = __shfl(lo, 32);
    const float4* __restrict__ x4 = (const float4*)x;
    float4 acc0 = {0,0,0,0}, acc1 = {0,0,0,0};
    for (int e0 = start; e0 < end; e0 += 16) {
        int ea = e0 + g, eb = ea + 8;
        if (ea < end) { int c = cols[ea]; float v = vals[ea]; float4 xr = x4[c * 8 + l];
            acc0.x = fmaf(xr.x, v, acc0.x); acc0.y = fmaf(xr.y, v, acc0.y);
            acc0.z = fmaf(xr.z, v, acc0.z); acc0.w = fmaf(xr.w, v, acc0.w); }
        if (eb < end) { int c = cols[eb]; float v = vals[eb]; float4 xr = x4[c * 8 + l];
            acc1.x = fmaf(xr.x, v, acc1.x); acc1.y = fmaf(xr.y, v, acc1.y);
            acc1.z = fmaf(xr.z, v, acc1.z); acc1.w = fmaf(xr.w, v, acc1.w); }
    }
    acc0.x += acc1.x; acc0.y += acc1.y; acc0.z += acc1.z; acc0.w += acc1.w;
    #pragma unroll
    for (int m = 8; m < 64; m <<= 1) {
        acc0.x += __shfl_xor(acc0.x, m); acc0.y += __shfl_xor(acc0.y, m);
        acc0.z += __shfl_xor(acc0.z, m); acc0.w += __shfl_xor(acc0.w, m);
    }
    float comp[4] = {acc0.x, acc0.y, acc0.z, acc0.w};
    int fo = lane & 31;
    float o = bS[fo];
    #pragma unroll
    for (int fi = 0; fi < F; ++fi)
        o = fmaf(__shfl(comp[fi & 3], fi >> 2), Wt[fi * F + fo], o);
    if (lane < F) out[n * F + fo] = fmaxf(o, 0.0f);
}

extern "C" void kernel_launch(void* const* d_in, const int* in_sizes, int n_in,
                              void* d_out, int out_size, void* d_ws, size_t ws_size,
                              hipStream_t stream) {
    const float* x    = (const float*)d_in[0];
    const int*   rows = (const int*)  d_in[1];
    const int*   cols = (const int*)  d_in[2];
    const float* vals = (const float*)d_in[3];
    const float* W    = (const float*)d_in[4];
    const float* bias = (const float*)d_in[5];
    float*       out  = (float*)d_out;

    int N = in_sizes[0] / F;
    int E = in_sizes[1];

    size_t rp_bytes = (size_t)(N + 1) * sizeof(int);
    size_t y_off    = (rp_bytes + 255) & ~(size_t)255;
    size_t need     = y_off + (size_t)N * F * sizeof(unsigned short);

    if (ws_size >= need) {
        int* row_ptr = (int*)d_ws;
        unsigned short* y = (unsigned short*)((char*)d_ws + y_off);
        int nxw  = (N + 7) / 8;
        int ncsr = (E + 1 + 255) / 256;
        prologue_kernel<<<nxw + ncsr, 256, 0, stream>>>(x, W, rows, y, row_ptr, N, E, nxw);
        gnn_kernel<<<(N + 63) / 64, 256, 0, stream>>>(y, cols, vals, row_ptr, bias, out, N);
    } else {
        gnn_fp32_kernel<<<(N + 3) / 4, 256, 0, stream>>>(
            x, rows, cols, vals, W, bias, out, N, E);
    }
}

// Round 6
// 113.528 us; speedup vs baseline: 1.3151x; 1.3151x over previous
//
#include <hip/hip_runtime.h>

#define F 32  // F_IN == F_OUT == 32

typedef __attribute__((ext_vector_type(8))) unsigned short us8;
typedef __attribute__((ext_vector_type(4))) float f4;

// ---- bf16 helpers (manual RNE) ----
static __device__ __forceinline__ unsigned short f2bf(float f) {
    unsigned int u = __float_as_uint(f);
    u += 0x7FFF + ((u >> 16) & 1);
    return (unsigned short)(u >> 16);
}
static __device__ __forceinline__ float bf2f(unsigned short s) {
    return __uint_as_float(((unsigned int)s) << 16);
}

// Fused prologue. Blocks [0, nxw): y = x @ W^T in bf16, 64 nodes/block.
// Blocks [nxw, ...): CSR row-ptr boundary scatter from sorted rows.
__global__ __launch_bounds__(256) void prologue_kernel(
    const float* __restrict__ x, const float* __restrict__ W,
    const int* __restrict__ rows,
    unsigned short* __restrict__ y, int* __restrict__ ptr,
    int N, int E, int nxw) {
    int b = blockIdx.x;
    int t = threadIdx.x;
    if (b < nxw) {
        __shared__ float Wt[F * F];        // Wt[fi*32+fo]
        __shared__ float xs[64 * F];       // 64 node rows
        #pragma unroll
        for (int k = 0; k < 4; ++k) {
            int i = t + k * 256;
            Wt[(i & 31) * F + (i >> 5)] = W[i];
        }
        int n0 = b * 64;
        // 64*32 floats = 512 float4; 2 per thread, coalesced.
        const f4* __restrict__ x4 = (const f4*)(x + (size_t)n0 * F);
        f4* __restrict__ xs4 = (f4*)xs;
        int limit4 = (N * F - n0 * F) >> 2;  // full f4s available
        #pragma unroll
        for (int k = 0; k < 2; ++k) {
            int i = t + k * 256;
            f4 z = {0.f, 0.f, 0.f, 0.f};
            xs4[i] = (i < limit4) ? x4[i] : z;
        }
        __syncthreads();
        int fo = t & 31;
        int j0 = (t >> 5) * 8;             // 8 consecutive nodes per thread
        #pragma unroll
        for (int j = 0; j < 8; ++j) {
            int nl = j0 + j;
            float acc = 0.0f;
            #pragma unroll
            for (int fi = 0; fi < F; ++fi)
                acc = fmaf(xs[nl * F + fi], Wt[fi * F + fo], acc);
            int n = n0 + nl;
            if (n < N) y[(size_t)n * F + fo] = f2bf(acc);
        }
    } else {
        int e = (b - nxw) * 256 + t;
        if (e > E) return;
        int prev = (e == 0) ? -1 : rows[e - 1];
        int cur  = (e == E) ? N  : rows[e];
        for (int r = prev + 1; r <= cur; ++r) ptr[r] = e;
    }
}

// Hot kernel: wave = 16 nodes x 4 lanes. Lane l of group g loads ushort8
// (16B = features 8l..8l+7 of a 64B bf16 row). 8-edge unroll with clamped
// predication -> ~10 gathers in flight per wave; 2 accumulator chains.
// Plain loads (L2 reuse of edge stream), NT only on the final store.
__global__ __launch_bounds__(256) void gnn_kernel(
    const unsigned short* __restrict__ y,
    const int*   __restrict__ cols,
    const float* __restrict__ vals,
    const int*   __restrict__ row_ptr,
    const float* __restrict__ bias,
    float*       __restrict__ out, int N) {
    int t = threadIdx.x;
    int lane = t & 63;
    int g = lane >> 2;           // node group 0..15
    int l = lane & 3;            // feature slice: 8l..8l+7
    int n = (blockIdx.x * 4 + (t >> 6)) * 16 + g;
    int start = 0, end = 0;
    if (n < N) { start = row_ptr[n]; end = row_ptr[n + 1]; }

    const us8* __restrict__ y8 = (const us8*)y;   // 4 x ushort8 per row

    float a0[8], a1[8];
    #pragma unroll
    for (int i = 0; i < 8; ++i) { a0[i] = 0.f; a1[i] = 0.f; }

    for (int e = start; e < end; e += 8) {
        int ec[8];
        #pragma unroll
        for (int k = 0; k < 8; ++k) {
            int ek = e + k;
            ec[k] = (ek < end) ? ek : (end - 1);   // clamp: always in-range
        }
        int c[8];
        #pragma unroll
        for (int k = 0; k < 8; ++k) c[k] = cols[ec[k]];
        float v[8];
        #pragma unroll
        for (int k = 0; k < 8; ++k) {
            float vv = vals[ec[k]];
            v[k] = (e + k < end) ? vv : 0.0f;      // predicate via value
        }
        us8 r[8];
        #pragma unroll
        for (int k = 0; k < 8; ++k) r[k] = y8[(size_t)c[k] * 4 + l];
        #pragma unroll
        for (int k = 0; k < 8; ++k) {
            float* a = (k & 1) ? a1 : a0;          // 2 chains
            #pragma unroll
            for (int i = 0; i < 8; ++i)
                a[i] = fmaf(bf2f(r[k][i]), v[k], a[i]);
        }
    }

    if (n < N) {
        const float* __restrict__ bp = bias + l * 8;
        f4 o0, o1;
        o0.x = fmaxf(a0[0] + a1[0] + bp[0], 0.f);
        o0.y = fmaxf(a0[1] + a1[1] + bp[1], 0.f);
        o0.z = fmaxf(a0[2] + a1[2] + bp[2], 0.f);
        o0.w = fmaxf(a0[3] + a1[3] + bp[3], 0.f);
        o1.x = fmaxf(a0[4] + a1[4] + bp[4], 0.f);
        o1.y = fmaxf(a0[5] + a1[5] + bp[5], 0.f);
        o1.z = fmaxf(a0[6] + a1[6] + bp[6], 0.f);
        o1.w = fmaxf(a0[7] + a1[7] + bp[7], 0.f);
        f4* op = (f4*)(out + (size_t)n * F + l * 8);
        __builtin_nontemporal_store(o0, op);
        __builtin_nontemporal_store(o1, op + 1);
    }
}

// ---- Fallback (ws too small): round-2 proven fp32 kernel ----
__global__ __launch_bounds__(256) void gnn_fp32_kernel(
    const float* __restrict__ x,
    const int*   __restrict__ rows,
    const int*   __restrict__ cols,
    const float* __restrict__ vals,
    const float* __restrict__ W,
    const float* __restrict__ bias,
    float*       __restrict__ out,
    int N, int E) {
    __shared__ float Wt[F * F];
    __shared__ float bS[F];
    int t = threadIdx.x;
    for (int i = t; i < F * F; i += 256)
        Wt[(i & 31) * F + (i >> 5)] = W[i];
    if (t < F) bS[t] = bias[t];
    __syncthreads();
    int lane = t & 63;
    int n = blockIdx.x * 4 + (t >> 6);
    if (n >= N) return;
    int g = lane >> 3, l = lane & 7;
    int target = n + (lane >> 5);
    int lo = 0, hi = E;
    while (lo < hi) { int mid = (lo + hi) >> 1; if (rows[mid] < target) lo = mid + 1; else hi = mid; }
    int start = __shfl(lo, 0), end = __shfl(lo, 32);
    const float4* __restrict__ x4 = (const float4*)x;
    float4 acc0 = {0,0,0,0}, acc1 = {0,0,0,0};
    for (int e0 = start; e0 < end; e0 += 16) {
        int ea = e0 + g, eb = ea + 8;
        if (ea < end) { int c = cols[ea]; float v = vals[ea]; float4 xr = x4[c * 8 + l];
            acc0.x = fmaf(xr.x, v, acc0.x); acc0.y = fmaf(xr.y, v, acc0.y);
            acc0.z = fmaf(xr.z, v, acc0.z); acc0.w = fmaf(xr.w, v, acc0.w); }
        if (eb < end) { int c = cols[eb]; float v = vals[eb]; float4 xr = x4[c * 8 + l];
            acc1.x = fmaf(xr.x, v, acc1.x); acc1.y = fmaf(xr.y, v, acc1.y);
            acc1.z = fmaf(xr.z, v, acc1.z); acc1.w = fmaf(xr.w, v, acc1.w); }
    }
    acc0.x += acc1.x; acc0.y += acc1.y; acc0.z += acc1.z; acc0.w += acc1.w;
    #pragma unroll
    for (int m = 8; m < 64; m <<= 1) {
        acc0.x += __shfl_xor(acc0.x, m); acc0.y += __shfl_xor(acc0.y, m);
        acc0.z += __shfl_xor(acc0.z, m); acc0.w += __shfl_xor(acc0.w, m);
    }
    float comp[4] = {acc0.x, acc0.y, acc0.z, acc0.w};
    int fo = lane & 31;
    float o = bS[fo];
    #pragma unroll
    for (int fi = 0; fi < F; ++fi)
        o = fmaf(__shfl(comp[fi & 3], fi >> 2), Wt[fi * F + fo], o);
    if (lane < F) out[n * F + fo] = fmaxf(o, 0.0f);
}

extern "C" void kernel_launch(void* const* d_in, const int* in_sizes, int n_in,
                              void* d_out, int out_size, void* d_ws, size_t ws_size,
                              hipStream_t stream) {
    const float* x    = (const float*)d_in[0];
    const int*   rows = (const int*)  d_in[1];
    const int*   cols = (const int*)  d_in[2];
    const float* vals = (const float*)d_in[3];
    const float* W    = (const float*)d_in[4];
    const float* bias = (const float*)d_in[5];
    float*       out  = (float*)d_out;

    int N = in_sizes[0] / F;
    int E = in_sizes[1];

    size_t rp_bytes = (size_t)(N + 1) * sizeof(int);
    size_t y_off    = (rp_bytes + 255) & ~(size_t)255;
    size_t need     = y_off + (size_t)N * F * sizeof(unsigned short);

    if (ws_size >= need) {
        int* row_ptr = (int*)d_ws;
        unsigned short* y = (unsigned short*)((char*)d_ws + y_off);
        int nxw  = (N + 63) / 64;
        int ncsr = (E + 1 + 255) / 256;
        prologue_kernel<<<nxw + ncsr, 256, 0, stream>>>(x, W, rows, y, row_ptr, N, E, nxw);
        gnn_kernel<<<(N + 63) / 64, 256, 0, stream>>>(y, cols, vals, row_ptr, bias, out, N);
    } else {
        gnn_fp32_kernel<<<(N + 3) / 4, 256, 0, stream>>>(
            x, rows, cols, vals, W, bias, out, N, E);
    }
}